// Round 6
// baseline (596.970 us; speedup 1.0000x reference)
//
#include <hip/hip_runtime.h>
#include <stdint.h>

// ManualLSTM: B=512, T=1024, D=64, U=128.
// R6: 256 blocks x 256 threads (4 waves, 1 wave/SIMD), 2 batch rows/block.
// vs R5: eliminated the 2x duplicated nonlinearity work. Each wave owns
// 32 u-columns (2 N-tiles x 4 gates = 8 scaled fp8 MFMAs, K=128); each lane
// owns exactly ONE (row,u) pair: ti_s=quad&1, prow=quad>>1, u=32w+16*ti_s+nlo.
// Per-SIMD trans/VALU issue halves; matrix-pipe work unchanged (~316 cyc/step).
// h stored as fp8-e4m3 in LDS; U-weights fp8 B-frags in VGPRs (unity scales);
// xproj x.W (K=64, bf16 MFMA) once per 8-step group into fp32 Gx (+bias).
// One lgkm-only barrier per step (x HBM prefetch stays in flight).

typedef __attribute__((ext_vector_type(8))) short short8;
typedef __attribute__((ext_vector_type(4))) short short4v;
typedef __attribute__((ext_vector_type(4))) float floatx4;
typedef __attribute__((ext_vector_type(4))) int   intx4;
typedef __attribute__((ext_vector_type(8))) int   intx8;

#define B_SZ   512
#define T_SZ   1024
#define D_SZ   64
#define U_SZ   128
#define ROWS   2              // batch rows per block
#define NBLK   (B_SZ / ROWS)  // 256 blocks
#define NTHR   256            // 4 waves, 1 wave/SIMD
#define A1STRB 160            // h row stride in BYTES (128 fp8 + 32 pad)
#define A2STR  72             // x row stride (64 + 8 pad) in bf16
#define GXSTR  524            // Gx row stride in fp32 (stagger: 524%32=12)

__device__ __forceinline__ short f2bf(float f) {
    uint32_t u = __builtin_bit_cast(uint32_t, f);
    uint32_t r = (u + 0x7fffu + ((u >> 16) & 1u)) >> 16;   // RNE
    return (short)r;
}
__device__ __forceinline__ float fsig(float x) {
    return __builtin_amdgcn_rcpf(1.0f + __builtin_amdgcn_exp2f(-1.4426950408889634f * x));
}
__device__ __forceinline__ float ftanh(float x) {
    return 1.0f - 2.0f * __builtin_amdgcn_rcpf(1.0f + __builtin_amdgcn_exp2f(2.8853900817779268f * x));
}
// barrier draining only LDS ops (NOT vmcnt -> global x prefetch stays in flight)
__device__ __forceinline__ void sync_lds() {
    asm volatile("s_waitcnt lgkmcnt(0)\n\ts_barrier" ::: "memory");
}

__global__ __launch_bounds__(NTHR, 1) void lstm_persistent(
    const float* __restrict__ xin,
    const float* __restrict__ Wf, const float* __restrict__ Uf, const float* __restrict__ bfp,
    const float* __restrict__ Wi, const float* __restrict__ Ui, const float* __restrict__ bip,
    const float* __restrict__ Wc, const float* __restrict__ Uc, const float* __restrict__ bcp,
    const float* __restrict__ Wo, const float* __restrict__ Uo, const float* __restrict__ bop,
    float* __restrict__ out)
{
    __shared__ float Gx[16 * GXSTR];                 // xproj+bias table (fp32)
    __shared__ __align__(16) char A1[2][2 * A1STRB]; // h as fp8-e4m3, dbuf by step parity
    __shared__ short A2[16 * A2STR];                 // x tile (bf16) for next group

    const int tid  = threadIdx.x;
    const int wave = tid >> 6;     // 0..3
    const int lane = tid & 63;
    const int quad = lane >> 4;    // 0..3
    const int nlo  = lane & 15;
    const int blk  = blockIdx.x;

    const int ti_s = quad & 1;                 // which of the wave's 2 u-tiles
    const int prow = quad >> 1;                // batch row this lane owns
    const int u_s  = 32 * wave + 16 * ti_s + nlo;   // this lane's hidden unit

    const float* Wg[4] = {Wf, Wi, Wc, Wo};
    const float* Ug[4] = {Uf, Ui, Uc, Uo};

    // ---- recurrent U as fp8 B-fragments (VGPRs): bU8[gate][ti] ----
    // B layout (16x16x128 f8f6f4): byte j of dword d = k = quad*32 + 4d + j; col n = nlo
    intx8 bU8[4][2];
#pragma unroll
    for (int g = 0; g < 4; ++g)
#pragma unroll
        for (int ti = 0; ti < 2; ++ti) {
            const int uc = 32 * wave + 16 * ti + nlo;
#pragma unroll
            for (int d = 0; d < 8; ++d) {
                const int k0 = quad * 32 + d * 4;
                int pk = __builtin_amdgcn_cvt_pk_fp8_f32(
                    Ug[g][(k0 + 0) * U_SZ + uc], Ug[g][(k0 + 1) * U_SZ + uc], 0, 0);
                pk = __builtin_amdgcn_cvt_pk_fp8_f32(
                    Ug[g][(k0 + 2) * U_SZ + uc], Ug[g][(k0 + 3) * U_SZ + uc], pk, 1);
                bU8[g][ti][d] = pk;
            }
        }
    // ---- input W as bf16 B-fragments (group xproj pass, K=64) ----
    short8 bW[4][2][2];
#pragma unroll
    for (int g = 0; g < 4; ++g)
#pragma unroll
        for (int ti = 0; ti < 2; ++ti) {
            const int uc = 32 * wave + 16 * ti + nlo;
#pragma unroll
            for (int kt = 0; kt < 2; ++kt)
#pragma unroll
                for (int j = 0; j < 8; ++j) {
                    int k = kt * 32 + quad * 8 + j;
                    bW[g][ti][kt][j] = f2bf(Wg[g][k * U_SZ + uc]);
                }
        }
    float biasT[2][4];
#pragma unroll
    for (int ti = 0; ti < 2; ++ti) {
        const int uc = 32 * wave + 16 * ti + nlo;
        biasT[ti][0] = bfp[uc]; biasT[ti][1] = bip[uc];
        biasT[ti][2] = bcp[uc]; biasT[ti][3] = bop[uc];
    }
    float c_st = 0.0f;

    // ---- x loader mapping: thread -> one float4 of the 16x64 x-tile ----
    const int xrow = tid >> 7;             // 0..1
    const int xj   = (tid >> 4) & 7;       // t offset in group
    const int xd   = (tid & 15) << 2;      // d (quads of floats)
    const float* xb = xin + ((size_t)(blk * ROWS + xrow) * T_SZ) * D_SZ + xd;

    // ---- prologue ----
    for (int i = tid; i < 2 * 2 * A1STRB; i += NTHR) ((char*)A1)[i] = 0;   // h(0)=0
    {   // stage x(group 0) into A2
        float4 v = *(const float4*)(xb + (size_t)xj * D_SZ);
        short4v p = {f2bf(v.x), f2bf(v.y), f2bf(v.z), f2bf(v.w)};
        *(short4v*)&A2[(2 * xj + xrow) * A2STR + xd] = p;
    }
    __syncthreads();
    {   // seed Gx with xproj(group 0) + bias
        const short* a2p = &A2[nlo * A2STR + quad * 8];
        short8 s0 = *(const short8*)a2p, s1 = *(const short8*)(a2p + 32);
#pragma unroll
        for (int ti = 0; ti < 2; ++ti) {
            floatx4 q[4];
#pragma unroll
            for (int g = 0; g < 4; ++g) {
                q[g] = (floatx4){0.f, 0.f, 0.f, 0.f};
                q[g] = __builtin_amdgcn_mfma_f32_16x16x32_bf16(s0, bW[g][ti][0], q[g], 0, 0, 0);
                q[g] = __builtin_amdgcn_mfma_f32_16x16x32_bf16(s1, bW[g][ti][1], q[g], 0, 0, 0);
            }
            const int uc = 32 * wave + 16 * ti + nlo;
#pragma unroll
            for (int r = 0; r < 4; ++r) {
                floatx4 wv = {q[0][r] + biasT[ti][0], q[1][r] + biasT[ti][1],
                              q[2][r] + biasT[ti][2], q[3][r] + biasT[ti][3]};
                *(floatx4*)&Gx[(quad * 4 + r) * GXSTR + 4 * uc] = wv;
            }
        }
    }
    float4 xr = *(const float4*)(xb + (size_t)(8 + xj) * D_SZ);   // x(group 1)
    __syncthreads();

    for (int g = 0; g < 128; ++g) {
#pragma unroll
        for (int j = 0; j < 8; ++j) {
            const int s = g * 8 + j;

            // stage x(g+1) into A2 (consumed at this group's j==7 seed)
            if (j == 0 && g < 127) {
                short4v p = {f2bf(xr.x), f2bf(xr.y), f2bf(xr.z), f2bf(xr.w)};
                *(short4v*)&A2[(2 * xj + xrow) * A2STR + xd] = p;
            }
            // HBM prefetch x(g+2); stays in flight across lgkm barriers
            if (j == 2 && g < 126) {
                xr = *(const float4*)(xb + (size_t)(8 * (g + 2) + xj) * D_SZ);
            }

            // ---- A fragment (h fp8, rows replicated via nlo&1) + gate-table read ----
            const char* ap = &A1[j & 1][(nlo & 1) * A1STRB + quad * 32];
            intx4 alo = *(const intx4*)(ap);
            intx4 ahi = *(const intx4*)(ap + 16);
            floatx4 gx = *(const floatx4*)&Gx[(2 * j + prow) * GXSTR + 4 * u_s];
            intx8 a8 = {alo.x, alo.y, alo.z, alo.w, ahi.x, ahi.y, ahi.z, ahi.w};

            // ---- recurrent GEMM: 2 tiles x 4 gates, one scaled fp8 MFMA each ----
            floatx4 acc[4][2];
#pragma unroll
            for (int gt = 0; gt < 4; ++gt)
#pragma unroll
                for (int ti = 0; ti < 2; ++ti) {
                    floatx4 z = (floatx4){0.f, 0.f, 0.f, 0.f};
                    acc[gt][ti] = __builtin_amdgcn_mfma_scale_f32_16x16x128_f8f6f4(
                        a8, bU8[gt][ti], z, 0, 0,
                        0, 0x7f7f7f7f,    // A scales = 1.0
                        0, 0x7f7f7f7f);   // B scales = 1.0
                }

            // ---- extract this lane's (prow, u_s): lane-constant selects ----
            float gv0 = (ti_s ? (prow ? acc[0][1][1] : acc[0][1][0])
                              : (prow ? acc[0][0][1] : acc[0][0][0])) + gx[0];
            float gv1 = (ti_s ? (prow ? acc[1][1][1] : acc[1][1][0])
                              : (prow ? acc[1][0][1] : acc[1][0][0])) + gx[1];
            float gv2 = (ti_s ? (prow ? acc[2][1][1] : acc[2][1][0])
                              : (prow ? acc[2][0][1] : acc[2][0][0])) + gx[2];
            float gv3 = (ti_s ? (prow ? acc[3][1][1] : acc[3][1][0])
                              : (prow ? acc[3][0][1] : acc[3][0][0])) + gx[3];

            // ---- gates + state update ----
            float f  = fsig(gv0);
            float ii = fsig(gv1);
            float ct = ftanh(gv2);
            float oo = fsig(gv3);
            c_st = f * c_st + ii * ct;
            float h = oo * ftanh(c_st);

            // h -> fp8 byte pair (even-nlo lane packs self+odd neighbor)
            float hnb = __shfl_xor(h, 1);
            if (s == T_SZ - 1) {
                out[(size_t)(blk * ROWS + prow) * U_SZ + u_s] = h;
            } else if ((nlo & 1) == 0) {
                int pk = __builtin_amdgcn_cvt_pk_fp8_f32(h, hnb, 0, 0);
                *(short*)&A1[(j & 1) ^ 1][prow * A1STRB + u_s] = (short)(pk & 0xffff);
            }

            // ---- group boundary: xproj GEMM for next group, spill to Gx ----
            if (j == 7 && g < 127) {
                const short* a2p = &A2[nlo * A2STR + quad * 8];
                short8 s0 = *(const short8*)a2p, s1 = *(const short8*)(a2p + 32);
                floatx4 q[4][2];
#pragma unroll
                for (int ti = 0; ti < 2; ++ti)
#pragma unroll
                    for (int gt = 0; gt < 4; ++gt) {
                        q[gt][ti] = (floatx4){0.f, 0.f, 0.f, 0.f};
                        q[gt][ti] = __builtin_amdgcn_mfma_f32_16x16x32_bf16(s0, bW[gt][ti][0], q[gt][ti], 0, 0, 0);
                        q[gt][ti] = __builtin_amdgcn_mfma_f32_16x16x32_bf16(s1, bW[gt][ti][1], q[gt][ti], 0, 0, 0);
                    }
                sync_lds();   // all waves' Gx reads (this group) complete
#pragma unroll
                for (int ti = 0; ti < 2; ++ti) {
                    const int uc = 32 * wave + 16 * ti + nlo;
#pragma unroll
                    for (int r = 0; r < 4; ++r) {
                        floatx4 wv = {q[0][ti][r] + biasT[ti][0], q[1][ti][r] + biasT[ti][1],
                                      q[2][ti][r] + biasT[ti][2], q[3][ti][r] + biasT[ti][3]};
                        *(floatx4*)&Gx[(quad * 4 + r) * GXSTR + 4 * uc] = wv;
                    }
                }
            }

            sync_lds();   // h(t+1)/A2/Gx visible; vm prefetch unbroken
        }
    }
}

extern "C" void kernel_launch(void* const* d_in, const int* in_sizes, int n_in,
                              void* d_out, int out_size, void* d_ws, size_t ws_size,
                              hipStream_t stream) {
    (void)in_sizes; (void)n_in; (void)d_ws; (void)ws_size; (void)out_size;
    const float* xin = (const float*)d_in[0];
    const float* Wf  = (const float*)d_in[1];
    const float* Uf  = (const float*)d_in[2];
    const float* bf  = (const float*)d_in[3];
    const float* Wi  = (const float*)d_in[4];
    const float* Ui  = (const float*)d_in[5];
    const float* bi  = (const float*)d_in[6];
    const float* Wc  = (const float*)d_in[7];
    const float* Uc  = (const float*)d_in[8];
    const float* bc  = (const float*)d_in[9];
    const float* Wo  = (const float*)d_in[10];
    const float* Uo  = (const float*)d_in[11];
    const float* bo  = (const float*)d_in[12];
    float* out = (float*)d_out;

    hipLaunchKernelGGL(lstm_persistent, dim3(NBLK), dim3(NTHR), 0, stream,
                       xin, Wf, Uf, bf, Wi, Ui, bi, Wc, Uc, bc, Wo, Uo, bo, out);
}

// Round 7
// 571.739 us; speedup vs baseline: 1.0441x; 1.0441x over previous
//
#include <hip/hip_runtime.h>
#include <stdint.h>

// ManualLSTM: B=512, T=1024, D=64, U=128.
// R7: 256 blocks x 512 threads (8 waves, 2/SIMD), 2 batch rows/block.
// Waves 0-3 = CONSUMERS (recurrent chain), waves 4-7 = PRODUCERS (xproj).
//  - Consumers: per step, lean chain: 2x ds_read_b128 (h fp8) + 1 b128 (Gx)
//    -> 8 scaled fp8 MFMAs (h.U, K=128) -> dual-ti trans (prow-only selects,
//    fills MFMA issue gaps) -> 1-byte fp8 h store -> lgkm-only barrier.
//  - Producers: load x straight from HBM into A-fragment registers, run the
//    x.W GEMM (bf16 16x16x32) for group g+1 spread 1 tile/step, spill raw
//    xproj into group-parity double-buffered Gx. No A2 staging, no j==7
//    burst, no second barrier on the consumer chain.
// Gx race-free: consumers read Gx[g&1], producers write Gx[(g+1)&1].

typedef __attribute__((ext_vector_type(8))) short short8;
typedef __attribute__((ext_vector_type(4))) float floatx4;
typedef __attribute__((ext_vector_type(4))) int   intx4;
typedef __attribute__((ext_vector_type(8))) int   intx8;

#define B_SZ   512
#define T_SZ   1024
#define D_SZ   64
#define U_SZ   128
#define ROWS   2
#define NBLK   (B_SZ / ROWS)   // 256 blocks
#define NTHR   512             // 8 waves: 0-3 consumers, 4-7 producers
#define A1STRB 160             // h row stride in BYTES (128 fp8 + 32 pad)
#define GXSTR  524             // Gx row stride in fp32

__device__ __forceinline__ short f2bf(float f) {
    uint32_t u = __builtin_bit_cast(uint32_t, f);
    uint32_t r = (u + 0x7fffu + ((u >> 16) & 1u)) >> 16;   // RNE
    return (short)r;
}
__device__ __forceinline__ float fsig(float x) {
    return __builtin_amdgcn_rcpf(1.0f + __builtin_amdgcn_exp2f(-1.4426950408889634f * x));
}
__device__ __forceinline__ float ftanh(float x) {
    return 1.0f - 2.0f * __builtin_amdgcn_rcpf(1.0f + __builtin_amdgcn_exp2f(2.8853900817779268f * x));
}
// barrier draining only LDS ops (NOT vmcnt -> producer global loads stay in flight)
__device__ __forceinline__ void sync_lds() {
    asm volatile("s_waitcnt lgkmcnt(0)\n\ts_barrier" ::: "memory");
}

__global__ __launch_bounds__(NTHR, 2) void lstm_persistent(
    const float* __restrict__ xin,
    const float* __restrict__ Wf, const float* __restrict__ Uf, const float* __restrict__ bfp,
    const float* __restrict__ Wi, const float* __restrict__ Ui, const float* __restrict__ bip,
    const float* __restrict__ Wc, const float* __restrict__ Uc, const float* __restrict__ bcp,
    const float* __restrict__ Wo, const float* __restrict__ Uo, const float* __restrict__ bop,
    float* __restrict__ out)
{
    __shared__ float Gx[2][16 * GXSTR];              // raw xproj, dbuf by group parity
    __shared__ __align__(8) char A1[2][2 * A1STRB];  // h fp8-e4m3, dbuf by step parity

    const int tid  = threadIdx.x;
    const int wave = tid >> 6;     // 0..7
    const int lane = tid & 63;
    const int quad = lane >> 4;    // 0..3
    const int nlo  = lane & 15;
    const int blk  = blockIdx.x;

    const float* Wg[4] = {Wf, Wi, Wc, Wo};
    const float* Ug[4] = {Uf, Ui, Uc, Uo};

    if (wave < 4) {
        // ======================= CONSUMER =======================
        const int ti_s = quad & 1;
        const int prow = quad >> 1;
        const int u_s  = 32 * wave + 16 * ti_s + nlo;

        // recurrent U as fp8 B-fragments: byte j of dword d -> k = quad*32+4d+j
        intx8 bU8[4][2];
#pragma unroll
        for (int g = 0; g < 4; ++g)
#pragma unroll
            for (int ti = 0; ti < 2; ++ti) {
                const int uc = 32 * wave + 16 * ti + nlo;
#pragma unroll
                for (int d = 0; d < 8; ++d) {
                    const int k0 = quad * 32 + d * 4;
                    int pk = __builtin_amdgcn_cvt_pk_fp8_f32(
                        Ug[g][(k0 + 0) * U_SZ + uc], Ug[g][(k0 + 1) * U_SZ + uc], 0, 0);
                    pk = __builtin_amdgcn_cvt_pk_fp8_f32(
                        Ug[g][(k0 + 2) * U_SZ + uc], Ug[g][(k0 + 3) * U_SZ + uc], pk, 1);
                    bU8[g][ti][d] = pk;
                }
            }
        const floatx4 bias4 = {bfp[u_s], bip[u_s], bcp[u_s], bop[u_s]};
        float c_st = 0.0f;

        // zero both h buffers (h(0)=0); consumer tids are 0..255
        for (int i = tid; i < 2 * 2 * A1STRB; i += 256) ((char*)A1)[i] = 0;
        __syncthreads();

        for (int g = 0; g < 128; ++g) {
            const float* GxR = &Gx[g & 1][0];
#pragma unroll
            for (int j = 0; j < 8; ++j) {
                // ---- reads first: h fragment (2x b128) then xproj (b128) ----
                const char* ap = &A1[j & 1][(nlo & 1) * A1STRB + quad * 32];
                intx4 alo = *(const intx4*)(ap);
                intx4 ahi = *(const intx4*)(ap + 16);
                floatx4 gx = *(const floatx4*)&GxR[(2 * j + prow) * GXSTR + 4 * u_s];
                intx8 a8 = {alo.x, alo.y, alo.z, alo.w, ahi.x, ahi.y, ahi.z, ahi.w};
                gx += bias4;

                // ---- 8 scaled fp8 MFMAs: ti0 gates first, then ti1 ----
                floatx4 acc0[4], acc1[4];
#pragma unroll
                for (int gt = 0; gt < 4; ++gt) {
                    floatx4 z = (floatx4){0.f, 0.f, 0.f, 0.f};
                    acc0[gt] = __builtin_amdgcn_mfma_scale_f32_16x16x128_f8f6f4(
                        a8, bU8[gt][0], z, 0, 0, 0, 0x7f7f7f7f, 0, 0x7f7f7f7f);
                }
#pragma unroll
                for (int gt = 0; gt < 4; ++gt) {
                    floatx4 z = (floatx4){0.f, 0.f, 0.f, 0.f};
                    acc1[gt] = __builtin_amdgcn_mfma_scale_f32_16x16x128_f8f6f4(
                        a8, bU8[gt][1], z, 0, 0, 0, 0x7f7f7f7f, 0, 0x7f7f7f7f);
                }

                // ---- dual-ti trans: path A needs only acc0 (starts in ti1's shadow) ----
                float gA0 = (prow ? acc0[0][1] : acc0[0][0]) + gx[0];
                float gA1 = (prow ? acc0[1][1] : acc0[1][0]) + gx[1];
                float gA2 = (prow ? acc0[2][1] : acc0[2][0]) + gx[2];
                float gA3 = (prow ? acc0[3][1] : acc0[3][0]) + gx[3];
                float fA = fsig(gA0), iA = fsig(gA1), cAt = ftanh(gA2), oA = fsig(gA3);
                float cA = fA * c_st + iA * cAt;
                float hA = oA * ftanh(cA);

                float gB0 = (prow ? acc1[0][1] : acc1[0][0]) + gx[0];
                float gB1 = (prow ? acc1[1][1] : acc1[1][0]) + gx[1];
                float gB2 = (prow ? acc1[2][1] : acc1[2][0]) + gx[2];
                float gB3 = (prow ? acc1[3][1] : acc1[3][0]) + gx[3];
                float fB = fsig(gB0), iB = fsig(gB1), cBt = ftanh(gB2), oB = fsig(gB3);
                float cB = fB * c_st + iB * cBt;
                float hB = oB * ftanh(cB);

                c_st = ti_s ? cB : cA;
                float h = ti_s ? hB : hA;

                if (g == 127 && j == 7) {
                    out[(size_t)(blk * ROWS + prow) * U_SZ + u_s] = h;
                } else {
                    int pk = __builtin_amdgcn_cvt_pk_fp8_f32(h, h, 0, 0);
                    A1[(j & 1) ^ 1][prow * A1STRB + u_s] = (char)(pk & 0xff);
                }
                sync_lds();
            }
        }
    } else {
        // ======================= PRODUCER =======================
        // wave p owns u-tiles {2p, 2p+1} x 4 gates = 8 N-tiles; 1 tile/step.
        const int p = wave - 4;
        const int brow  = nlo & 1;     // A-frag row m=nlo -> (t_off, brow)
        const int t_off = nlo >> 1;

        // bW fragments for 8 tiles (tau: gt=tau>>1, ut=2p+(tau&1)), K=64 (2 kt)
        short8 bWp[8][2];
#pragma unroll
        for (int tau = 0; tau < 8; ++tau) {
            const int gt = tau >> 1;
            const int uc = 16 * (2 * p + (tau & 1)) + nlo;
#pragma unroll
            for (int kt = 0; kt < 2; ++kt)
#pragma unroll
                for (int jj = 0; jj < 8; ++jj) {
                    int k = kt * 32 + quad * 8 + jj;
                    bWp[tau][kt][jj] = f2bf(Wg[gt][k * U_SZ + uc]);
                }
        }

        const float* xg = xin + ((size_t)(blk * ROWS + brow) * T_SZ) * D_SZ + quad * 8;

        // ---- prologue: xproj(0) -> Gx[0]; xa = x(1); xq = x(2) in flight ----
        float4 p0 = *(const float4*)(xg + (size_t)t_off * D_SZ + 0);
        float4 p1 = *(const float4*)(xg + (size_t)t_off * D_SZ + 4);
        float4 p2 = *(const float4*)(xg + (size_t)t_off * D_SZ + 32);
        float4 p3 = *(const float4*)(xg + (size_t)t_off * D_SZ + 36);
        float4 q0 = *(const float4*)(xg + (size_t)(8 + t_off) * D_SZ + 0);
        float4 q1 = *(const float4*)(xg + (size_t)(8 + t_off) * D_SZ + 4);
        float4 q2 = *(const float4*)(xg + (size_t)(8 + t_off) * D_SZ + 32);
        float4 q3 = *(const float4*)(xg + (size_t)(8 + t_off) * D_SZ + 36);

        short8 xa0 = {f2bf(p0.x), f2bf(p0.y), f2bf(p0.z), f2bf(p0.w),
                      f2bf(p1.x), f2bf(p1.y), f2bf(p1.z), f2bf(p1.w)};
        short8 xa1 = {f2bf(p2.x), f2bf(p2.y), f2bf(p2.z), f2bf(p2.w),
                      f2bf(p3.x), f2bf(p3.y), f2bf(p3.z), f2bf(p3.w)};
#pragma unroll
        for (int tau = 0; tau < 8; ++tau) {
            const int gt = tau >> 1;
            const int uc = 16 * (2 * p + (tau & 1)) + nlo;
            floatx4 acc = (floatx4){0.f, 0.f, 0.f, 0.f};
            acc = __builtin_amdgcn_mfma_f32_16x16x32_bf16(xa0, bWp[tau][0], acc, 0, 0, 0);
            acc = __builtin_amdgcn_mfma_f32_16x16x32_bf16(xa1, bWp[tau][1], acc, 0, 0, 0);
#pragma unroll
            for (int r = 0; r < 4; ++r)
                Gx[0][(quad * 4 + r) * GXSTR + 4 * uc + gt] = acc[r];
        }
        // xa = x(1)
        xa0 = (short8){f2bf(q0.x), f2bf(q0.y), f2bf(q0.z), f2bf(q0.w),
                       f2bf(q1.x), f2bf(q1.y), f2bf(q1.z), f2bf(q1.w)};
        xa1 = (short8){f2bf(q2.x), f2bf(q2.y), f2bf(q2.z), f2bf(q2.w),
                       f2bf(q3.x), f2bf(q3.y), f2bf(q3.z), f2bf(q3.w)};
        // xq = x(2), in flight
        float4 xq0 = *(const float4*)(xg + (size_t)(16 + t_off) * D_SZ + 0);
        float4 xq1 = *(const float4*)(xg + (size_t)(16 + t_off) * D_SZ + 4);
        float4 xq2 = *(const float4*)(xg + (size_t)(16 + t_off) * D_SZ + 32);
        float4 xq3 = *(const float4*)(xg + (size_t)(16 + t_off) * D_SZ + 36);
        __syncthreads();

        short8 xn0 = xa0, xn1 = xa1;
        for (int g = 0; g < 128; ++g) {
            float* GxW = &Gx[(g + 1) & 1][0];
#pragma unroll
            for (int j = 0; j < 8; ++j) {
                if (j == 0 && g <= 125) {   // cvt xq -> x(g+2) frags
                    xn0 = (short8){f2bf(xq0.x), f2bf(xq0.y), f2bf(xq0.z), f2bf(xq0.w),
                                   f2bf(xq1.x), f2bf(xq1.y), f2bf(xq1.z), f2bf(xq1.w)};
                    xn1 = (short8){f2bf(xq2.x), f2bf(xq2.y), f2bf(xq2.z), f2bf(xq2.w),
                                   f2bf(xq3.x), f2bf(xq3.y), f2bf(xq3.z), f2bf(xq3.w)};
                }
                if (j == 1 && g <= 124) {   // issue loads of x(g+3)
                    const float* b = xg + (size_t)(8 * (g + 3) + t_off) * D_SZ;
                    xq0 = *(const float4*)(b + 0);
                    xq1 = *(const float4*)(b + 4);
                    xq2 = *(const float4*)(b + 32);
                    xq3 = *(const float4*)(b + 36);
                }
                if (g < 127) {              // tile tau=j of xproj(g+1)
                    const int gt = j >> 1;
                    const int uc = 16 * (2 * p + (j & 1)) + nlo;
                    floatx4 acc = (floatx4){0.f, 0.f, 0.f, 0.f};
                    acc = __builtin_amdgcn_mfma_f32_16x16x32_bf16(xa0, bWp[j][0], acc, 0, 0, 0);
                    acc = __builtin_amdgcn_mfma_f32_16x16x32_bf16(xa1, bWp[j][1], acc, 0, 0, 0);
#pragma unroll
                    for (int r = 0; r < 4; ++r)
                        GxW[(quad * 4 + r) * GXSTR + 4 * uc + gt] = acc[r];
                }
                sync_lds();
            }
            xa0 = xn0; xa1 = xn1;
        }
    }
}

extern "C" void kernel_launch(void* const* d_in, const int* in_sizes, int n_in,
                              void* d_out, int out_size, void* d_ws, size_t ws_size,
                              hipStream_t stream) {
    (void)in_sizes; (void)n_in; (void)d_ws; (void)ws_size; (void)out_size;
    const float* xin = (const float*)d_in[0];
    const float* Wf  = (const float*)d_in[1];
    const float* Uf  = (const float*)d_in[2];
    const float* bf  = (const float*)d_in[3];
    const float* Wi  = (const float*)d_in[4];
    const float* Ui  = (const float*)d_in[5];
    const float* bi  = (const float*)d_in[6];
    const float* Wc  = (const float*)d_in[7];
    const float* Uc  = (const float*)d_in[8];
    const float* bc  = (const float*)d_in[9];
    const float* Wo  = (const float*)d_in[10];
    const float* Uo  = (const float*)d_in[11];
    const float* bo  = (const float*)d_in[12];
    float* out = (float*)d_out;

    hipLaunchKernelGGL(lstm_persistent, dim3(NBLK), dim3(NTHR), 0, stream,
                       xin, Wf, Uf, bf, Wi, Ui, bi, Wc, Uc, bc, Wo, Uo, bo, out);
}